// Round 3
// baseline (1321.378 us; speedup 1.0000x reference)
//
#include <hip/hip_runtime.h>

// MAB (gMLP mixing block) — round 3: fp32 I/O (reference dtype), bf16
// internal workspace, row-chunked VALU pipeline.
//
// Round-1/2 NaN root cause: inputs are float32 (per reference); reading them
// as bf16 words decodes random mantissa halves, ~0.4% NaN patterns -> LN1
// spreads NaN everywhere. All global inputs/outputs now fp32; weights are
// converted fp32->bf16 while staging into LDS; intermediates stay bf16.
//
// Dims: B=2, H=W=256, C=128, S=16, G=256, N=256, CI=64, F1=384, HF=192.
// Rows R = 2(branch)*2(B)*256(G) = 1024; chunk RC = 256.
//
//  K1: LN1 + [131072x128]x[128x128] GEMM + GELU -> xin[r][n][ci]   (full)
//  per chunk:
//   K2: LN2 + per-n E1 + GELU + LN3(u) -> u_ln[r][n][f], v[r][n][f]
//   T1: u_ln -> uT[c][r][n]
//   K3: per-c SGU [256x256]x[256x256] + bsgu -> sT[c][r][m]
//   T2: t[r][m][c] = sT[c][r][m] * v[r][m][c]
//   K4: per-n E2 + b2 + xin residual + recon/concat + outer residual (fp32 out)
//
// ws (bf16 elems): xin 16,777,216 | bufA 12,582,912 | bufV 12,582,912 |
// bufB 12,582,912  => 109,051,904 bytes.

typedef unsigned int uint_t;
typedef unsigned short us_t;

#define EPSF 1e-3f

__device__ __forceinline__ float b2f(us_t h){ return __uint_as_float(((uint_t)h) << 16); }
__device__ __forceinline__ float lo2f(uint_t u){ return __uint_as_float(u << 16); }
__device__ __forceinline__ float hi2f(uint_t u){ return __uint_as_float(u & 0xFFFF0000u); }
__device__ __forceinline__ us_t f2b(float f){
  uint_t u = __float_as_uint(f);
  uint_t r = (u + 0x7FFFu + ((u >> 16) & 1u)) >> 16;
  return (us_t)r;
}
__device__ __forceinline__ uint_t pack2(float a, float b){
  return (uint_t)f2b(a) | ((uint_t)f2b(b) << 16);
}
__device__ __forceinline__ float gelu_f(float v){
  return 0.5f*v*(1.f + erff(v*0.7071067811865475f));
}

// ---------------------------------------------------------------- K1
// 32 pixels/block. LDS: xs2 [128 c][40 pix] f32 (20K) + Ws bf16 (32K).
__global__ __launch_bounds__(256) void k1_ln_proj(
    const float* __restrict__ x, const float* __restrict__ g1, const float* __restrict__ b1l,
    const float* __restrict__ Wp, const float* __restrict__ bp, us_t* __restrict__ xin)
{
  __shared__ __align__(16) float xs2[128*40];   // [c][pix], stride 40
  __shared__ __align__(16) us_t Ws[128*128];
  int t = threadIdx.x;
  int p0 = blockIdx.x * 32;

  { // stage x transposed: thread = (pixel t>>3, 16 channels at (t&7)*16)
    int pi = t >> 3, c0 = (t & 7) << 4;
    const float* src = x + (size_t)(p0 + pi)*128 + c0;
    float4 d0 = *(const float4*)src;
    float4 d1 = *(const float4*)(src + 4);
    float4 d2 = *(const float4*)(src + 8);
    float4 d3 = *(const float4*)(src + 12);
    float* dst = &xs2[c0*40 + pi];
    dst[0]   = d0.x; dst[40]  = d0.y; dst[80]  = d0.z; dst[120] = d0.w;
    dst[160] = d1.x; dst[200] = d1.y; dst[240] = d1.z; dst[280] = d1.w;
    dst[320] = d2.x; dst[360] = d2.y; dst[400] = d2.z; dst[440] = d2.w;
    dst[480] = d3.x; dst[520] = d3.y; dst[560] = d3.z; dst[600] = d3.w;
  }
  #pragma unroll
  for (int i = 0; i < 16; i++){   // Wp fp32 -> bf16 LDS
    int idx = (i*256 + t)*4;
    float4 w = *(const float4*)(Wp + idx);
    *(uint2*)&Ws[idx] = make_uint2(pack2(w.x,w.y), pack2(w.z,w.w));
  }
  __syncthreads();
  { // LN1: wave handles 8 pixels; lane owns channels ln, ln+64
    int wv = t >> 6, ln = t & 63;
    float ga = g1[ln], gb = g1[ln+64];
    float ba = b1l[ln], bb = b1l[ln+64];
    for (int k = 0; k < 8; k++){
      int pi = wv*8 + k;
      float a = xs2[ln*40 + pi];
      float c = xs2[(ln+64)*40 + pi];
      float s = a + c, q = a*a + c*c;
      #pragma unroll
      for (int off = 32; off; off >>= 1){ s += __shfl_xor(s, off, 64); q += __shfl_xor(q, off, 64); }
      float m = s*(1.f/128.f);
      float rstd = rsqrtf(q*(1.f/128.f) - m*m + EPSF);
      xs2[ln*40 + pi]      = (a - m)*rstd*ga + ba;
      xs2[(ln+64)*40 + pi] = (c - m)*rstd*gb + bb;
    }
  }
  __syncthreads();
  // GEMM: thread = 4 pixels x 4 couts
  int cg = t & 31, pg = t >> 5;
  int co0 = cg*4, p00 = pg*4;
  float acc[4][4] = {};
  #pragma unroll 4
  for (int ci = 0; ci < 128; ci++){
    float4 xv = *(const float4*)&xs2[ci*40 + p00];
    uint2 wv2 = *(const uint2*)&Ws[ci*128 + co0];
    float w0 = lo2f(wv2.x), w1 = hi2f(wv2.x), w2 = lo2f(wv2.y), w3 = hi2f(wv2.y);
    acc[0][0] += xv.x*w0; acc[0][1] += xv.x*w1; acc[0][2] += xv.x*w2; acc[0][3] += xv.x*w3;
    acc[1][0] += xv.y*w0; acc[1][1] += xv.y*w1; acc[1][2] += xv.y*w2; acc[1][3] += xv.y*w3;
    acc[2][0] += xv.z*w0; acc[2][1] += xv.z*w1; acc[2][2] += xv.z*w2; acc[2][3] += xv.z*w3;
    acc[3][0] += xv.w*w0; acc[3][1] += xv.w*w1; acc[3][2] += xv.w*w2; acc[3][3] += xv.w*w3;
  }
  float bb0 = bp[co0],   bb1 = bp[co0+1];
  float bb2 = bp[co0+2], bb3 = bp[co0+3];
  int branch = co0 >> 6;
  int c = co0 & 63;
  #pragma unroll
  for (int i = 0; i < 4; i++){
    int p = p0 + p00 + i;
    int b = p >> 16, rem = p & 65535, h = rem >> 8, w = rem & 255;
    int g = ((h >> 4) << 4) | (w >> 4);      // make_blocks head index
    int nn = ((h & 15) << 4) | (w & 15);     // patch within head
    float y0 = gelu_f(acc[i][0] + bb0);
    float y1 = gelu_f(acc[i][1] + bb1);
    float y2 = gelu_f(acc[i][2] + bb2);
    float y3 = gelu_f(acc[i][3] + bb3);
    size_t row = (size_t)branch*512 + (size_t)b*256 + g;
    *(uint2*)(xin + (row*256 + nn)*64 + c) = make_uint2(pack2(y0,y1), pack2(y2,y3));
  }
}

// ---------------------------------------------------------------- K2 (chunked)
// grid = 256 n x 8 rt. LDS: Wl bf16 48K + xs2 f32 9K + b1s f32 1.5K.
__global__ __launch_bounds__(256) void k2_e1(
    const us_t* __restrict__ xin,
    const float* __restrict__ g2, const float* __restrict__ b2l,
    const float* __restrict__ W1, const float* __restrict__ b1v,
    const float* __restrict__ g3, const float* __restrict__ b3l,
    us_t* __restrict__ u_ln, us_t* __restrict__ vout, int r_base)
{
  __shared__ __align__(16) us_t Wl[64*384];
  __shared__ __align__(16) float xs2[64*36];
  __shared__ float b1s[384];
  int t = threadIdx.x;
  int n = blockIdx.x >> 3, rt = blockIdx.x & 7;

  const float* wsrc = W1 + (size_t)n*24576;
  #pragma unroll
  for (int i = 0; i < 24; i++){   // W1 fp32 -> bf16 LDS
    int idx = (i*256 + t)*4;
    float4 w = *(const float4*)(wsrc + idx);
    *(uint2*)&Wl[idx] = make_uint2(pack2(w.x,w.y), pack2(w.z,w.w));
  }
  if (t < 96){
    float4 d = *(const float4*)(b1v + n*384 + t*4);
    b1s[t*4+0] = d.x; b1s[t*4+1] = d.y; b1s[t*4+2] = d.z; b1s[t*4+3] = d.w;
  }
  { // stage xin rows transposed [ci][row] (bf16 internal)
    int rr = t >> 3, cc0 = (t & 7) << 3;
    uint4 d = *(const uint4*)(xin + ((size_t)(r_base + rt*32 + rr)*256 + n)*64 + cc0);
    float* dst = &xs2[cc0*36 + rr];
    dst[0]    = lo2f(d.x); dst[36]   = hi2f(d.x);
    dst[2*36] = lo2f(d.y); dst[3*36] = hi2f(d.y);
    dst[4*36] = lo2f(d.z); dst[5*36] = hi2f(d.z);
    dst[6*36] = lo2f(d.w); dst[7*36] = hi2f(d.w);
  }
  __syncthreads();
  { // LN2: wave handles 8 rows, lane = channel
    int wv = t >> 6, ln = t & 63;
    float gch = g2[ln], bch = b2l[ln];
    for (int k = 0; k < 8; k++){
      int row = wv*8 + k;
      float a = xs2[ln*36 + row];
      float s = a, q = a*a;
      #pragma unroll
      for (int off = 32; off; off >>= 1){ s += __shfl_xor(s, off, 64); q += __shfl_xor(q, off, 64); }
      float m = s*(1.f/64.f);
      float rstd = rsqrtf(q*(1.f/64.f) - m*m + EPSF);
      xs2[ln*36 + row] = (a - m)*rstd*gch + bch;
    }
  }
  __syncthreads();
  // E1 GEMM: thread = 4 rows x 12 f
  int fg = t & 31, rg = t >> 5;
  int f0 = fg*12, r00 = rg*4;
  float acc[4][12] = {};
  #pragma unroll 4
  for (int ci = 0; ci < 64; ci++){
    float4 xv = *(const float4*)&xs2[ci*36 + r00];
    const uint2* wp2 = (const uint2*)&Wl[ci*384 + f0];
    uint2 wa = wp2[0], wb = wp2[1], wc = wp2[2];
    float wf[12];
    wf[0]=lo2f(wa.x); wf[1]=hi2f(wa.x); wf[2]=lo2f(wa.y); wf[3]=hi2f(wa.y);
    wf[4]=lo2f(wb.x); wf[5]=hi2f(wb.x); wf[6]=lo2f(wb.y); wf[7]=hi2f(wb.y);
    wf[8]=lo2f(wc.x); wf[9]=hi2f(wc.x); wf[10]=lo2f(wc.y); wf[11]=hi2f(wc.y);
    float xa[4] = {xv.x, xv.y, xv.z, xv.w};
    #pragma unroll
    for (int i = 0; i < 4; i++)
      #pragma unroll
      for (int j = 0; j < 12; j++)
        acc[i][j] += xa[i]*wf[j];
  }
  // bias + gelu; partial sums for LN3 (u half = fg<16, 32-lane group)
  bool isu = (fg < 16);
  float s4[4], q4[4];
  #pragma unroll
  for (int i = 0; i < 4; i++){
    float s = 0.f, q = 0.f;
    #pragma unroll
    for (int j = 0; j < 12; j++){
      float yv = gelu_f(acc[i][j] + b1s[f0 + j]);
      acc[i][j] = yv;
      s += yv; q += yv*yv;
    }
    s4[i] = isu ? s : 0.f;
    q4[i] = isu ? q : 0.f;
  }
  #pragma unroll
  for (int i = 0; i < 4; i++){
    float s = s4[i], q = q4[i];
    #pragma unroll
    for (int off = 16; off; off >>= 1){ s += __shfl_xor(s, off, 64); q += __shfl_xor(q, off, 64); }
    float m = s*(1.f/192.f);
    s4[i] = m;
    q4[i] = rsqrtf(q*(1.f/192.f) - m*m + EPSF);
  }
  if (isu){
    float gv[12], bv[12];
    #pragma unroll
    for (int j = 0; j < 12; j++){ gv[j] = g3[f0+j]; bv[j] = b3l[f0+j]; }
    #pragma unroll
    for (int i = 0; i < 4; i++){
      int r = rt*32 + r00 + i;                 // chunk-local
      float m = s4[i], rstd = q4[i];
      uint2* dst = (uint2*)(u_ln + ((size_t)r*256 + n)*192 + f0);
      uint2 o0, o1, o2;
      o0.x = pack2((acc[i][0]-m)*rstd*gv[0]+bv[0],  (acc[i][1]-m)*rstd*gv[1]+bv[1]);
      o0.y = pack2((acc[i][2]-m)*rstd*gv[2]+bv[2],  (acc[i][3]-m)*rstd*gv[3]+bv[3]);
      o1.x = pack2((acc[i][4]-m)*rstd*gv[4]+bv[4],  (acc[i][5]-m)*rstd*gv[5]+bv[5]);
      o1.y = pack2((acc[i][6]-m)*rstd*gv[6]+bv[6],  (acc[i][7]-m)*rstd*gv[7]+bv[7]);
      o2.x = pack2((acc[i][8]-m)*rstd*gv[8]+bv[8],  (acc[i][9]-m)*rstd*gv[9]+bv[9]);
      o2.y = pack2((acc[i][10]-m)*rstd*gv[10]+bv[10],(acc[i][11]-m)*rstd*gv[11]+bv[11]);
      dst[0] = o0; dst[1] = o1; dst[2] = o2;
    }
  } else {
    int fv0 = f0 - 192;
    #pragma unroll
    for (int i = 0; i < 4; i++){
      int r = rt*32 + r00 + i;                 // chunk-local
      uint2* dst = (uint2*)(vout + ((size_t)r*256 + n)*192 + fv0);
      uint2 o0, o1, o2;
      o0.x = pack2(acc[i][0], acc[i][1]);  o0.y = pack2(acc[i][2], acc[i][3]);
      o1.x = pack2(acc[i][4], acc[i][5]);  o1.y = pack2(acc[i][6], acc[i][7]);
      o2.x = pack2(acc[i][8], acc[i][9]);  o2.y = pack2(acc[i][10], acc[i][11]);
      dst[0] = o0; dst[1] = o1; dst[2] = o2;
    }
  }
}

// ---------------------------------------------------------------- T1 (chunked)
// u_ln[r][n][c] -> uT[c][r][n], r in [0,256)
__global__ __launch_bounds__(256) void t1_transpose(const us_t* __restrict__ u_ln, us_t* __restrict__ uT){
  __shared__ us_t ls[128*194];
  int t = threadIdx.x;
  int r = blockIdx.x >> 1, n0 = (blockIdx.x & 1) << 7;
  #pragma unroll
  for (int i = 0; i < 12; i++){
    int chunk = i*256 + t;
    int nn = chunk/24, c0 = (chunk - nn*24)*8;
    uint4 d = *(const uint4*)(u_ln + ((size_t)r*256 + n0 + nn)*192 + c0);
    us_t* dst = &ls[nn*194 + c0];
    dst[0] = (us_t)d.x; dst[1] = (us_t)(d.x>>16);
    dst[2] = (us_t)d.y; dst[3] = (us_t)(d.y>>16);
    dst[4] = (us_t)d.z; dst[5] = (us_t)(d.z>>16);
    dst[6] = (us_t)d.w; dst[7] = (us_t)(d.w>>16);
  }
  __syncthreads();
  #pragma unroll
  for (int i = 0; i < 12; i++){
    int chunk = i*256 + t;
    int c = chunk >> 4, nn0 = (chunk & 15) << 3;
    const us_t* sp = &ls[nn0*194 + c];
    uint4 o;
    o.x = (uint_t)sp[0]     | ((uint_t)sp[194]   << 16);
    o.y = (uint_t)sp[2*194] | ((uint_t)sp[3*194] << 16);
    o.z = (uint_t)sp[4*194] | ((uint_t)sp[5*194] << 16);
    o.w = (uint_t)sp[6*194] | ((uint_t)sp[7*194] << 16);
    *(uint4*)(uT + ((size_t)c*256 + r)*256 + n0 + nn0) = o;
  }
}

// ---------------------------------------------------------------- K3 (chunked)
// per-c SGU: [256x256]x[256x256]. grid = 192 c x 2 rt x 2 mt.
__global__ __launch_bounds__(256) void k3_sgu(
    const us_t* __restrict__ uT, const float* __restrict__ Wsgu,
    const float* __restrict__ bsgu, us_t* __restrict__ sT)
{
  __shared__ __align__(16) us_t As[64*136];
  __shared__ __align__(16) us_t Bs[64*136];
  int t = threadIdx.x;
  int bid = blockIdx.x;
  int c = bid >> 2, rt = (bid >> 1) & 1, mt = bid & 1;
  int r0 = (t >> 4) << 3, m0 = (t & 15) << 3;
  float acc[8][8] = {};

  for (int kt = 0; kt < 4; kt++){
    #pragma unroll
    for (int i = 0; i < 4; i++){       // stage A (bf16, transposed to [k][r])
      int chunk = i*256 + t;
      int rr = chunk >> 3, kk0 = (chunk & 7) << 3;
      uint4 d = *(const uint4*)(uT + (c*256 + rt*128 + rr)*256 + kt*64 + kk0);
      us_t* dst = &As[kk0*136 + rr];
      dst[0]     = (us_t)d.x; dst[136]   = (us_t)(d.x>>16);
      dst[2*136] = (us_t)d.y; dst[3*136] = (us_t)(d.y>>16);
      dst[4*136] = (us_t)d.z; dst[5*136] = (us_t)(d.z>>16);
      dst[6*136] = (us_t)d.w; dst[7*136] = (us_t)(d.w>>16);
    }
    #pragma unroll
    for (int i = 0; i < 8; i++){       // stage B: Wsgu fp32 -> bf16 [k][m]
      int chunk = i*256 + t;
      int kk = chunk >> 5, mm0 = (chunk & 31) << 2;
      float4 w = *(const float4*)(Wsgu + ((size_t)(c*256 + kt*64 + kk))*256 + mt*128 + mm0);
      *(uint2*)&Bs[kk*136 + mm0] = make_uint2(pack2(w.x,w.y), pack2(w.z,w.w));
    }
    __syncthreads();
    #pragma unroll 4
    for (int k = 0; k < 64; k++){
      uint4 au = *(const uint4*)&As[k*136 + r0];
      uint4 bu = *(const uint4*)&Bs[k*136 + m0];
      float av[8], bv[8];
      av[0]=lo2f(au.x); av[1]=hi2f(au.x); av[2]=lo2f(au.y); av[3]=hi2f(au.y);
      av[4]=lo2f(au.z); av[5]=hi2f(au.z); av[6]=lo2f(au.w); av[7]=hi2f(au.w);
      bv[0]=lo2f(bu.x); bv[1]=hi2f(bu.x); bv[2]=lo2f(bu.y); bv[3]=hi2f(bu.y);
      bv[4]=lo2f(bu.z); bv[5]=hi2f(bu.z); bv[6]=lo2f(bu.w); bv[7]=hi2f(bu.w);
      #pragma unroll
      for (int i = 0; i < 8; i++)
        #pragma unroll
        for (int j = 0; j < 8; j++)
          acc[i][j] += av[i]*bv[j];
    }
    __syncthreads();
  }
  float4 ba = *(const float4*)(bsgu + c*256 + mt*128 + m0);
  float4 bb = *(const float4*)(bsgu + c*256 + mt*128 + m0 + 4);
  float bfv[8] = {ba.x, ba.y, ba.z, ba.w, bb.x, bb.y, bb.z, bb.w};
  #pragma unroll
  for (int i = 0; i < 8; i++){
    uint4 o;
    o.x = pack2(acc[i][0]+bfv[0], acc[i][1]+bfv[1]);
    o.y = pack2(acc[i][2]+bfv[2], acc[i][3]+bfv[3]);
    o.z = pack2(acc[i][4]+bfv[4], acc[i][5]+bfv[5]);
    o.w = pack2(acc[i][6]+bfv[6], acc[i][7]+bfv[7]);
    *(uint4*)(sT + (c*256 + rt*128 + r0 + i)*256 + mt*128 + m0) = o;
  }
}

// ---------------------------------------------------------------- T2 (chunked)
// t[r][m][c] = sT[c][r][m] * v[r][m][c], r in [0,256)
__global__ __launch_bounds__(256) void t2_mul(
    const us_t* __restrict__ sT, const us_t* __restrict__ v, us_t* __restrict__ tout)
{
  __shared__ us_t ls[192*130];
  int t = threadIdx.x;
  int r = blockIdx.x >> 1, m0 = (blockIdx.x & 1) << 7;
  #pragma unroll
  for (int i = 0; i < 12; i++){
    int chunk = i*256 + t;
    int c = chunk >> 4, mm0 = (chunk & 15) << 3;
    uint4 d = *(const uint4*)(sT + ((size_t)c*256 + r)*256 + m0 + mm0);
    us_t* dst = &ls[c*130 + mm0];
    dst[0] = (us_t)d.x; dst[1] = (us_t)(d.x>>16);
    dst[2] = (us_t)d.y; dst[3] = (us_t)(d.y>>16);
    dst[4] = (us_t)d.z; dst[5] = (us_t)(d.z>>16);
    dst[6] = (us_t)d.w; dst[7] = (us_t)(d.w>>16);
  }
  __syncthreads();
  #pragma unroll
  for (int i = 0; i < 12; i++){
    int chunk = i*256 + t;
    int mm = chunk/24, c0 = (chunk - mm*24)*8;
    size_t gidx = ((size_t)r*256 + m0 + mm)*192 + c0;
    uint4 vv = *(const uint4*)(v + gidx);
    const us_t* sp = &ls[c0*130 + mm];
    uint4 o;
    o.x = pack2(b2f(sp[0])*lo2f(vv.x),     b2f(sp[130])*hi2f(vv.x));
    o.y = pack2(b2f(sp[2*130])*lo2f(vv.y), b2f(sp[3*130])*hi2f(vv.y));
    o.z = pack2(b2f(sp[4*130])*lo2f(vv.z), b2f(sp[5*130])*hi2f(vv.z));
    o.w = pack2(b2f(sp[6*130])*lo2f(vv.w), b2f(sp[7*130])*hi2f(vv.w));
    *(uint4*)(tout + gidx) = o;
  }
}

// ---------------------------------------------------------------- K4 (chunked)
// per-n E2 + b2 + xin residual + recon/concat + outer residual (fp32 out).
__global__ __launch_bounds__(256) void k4_out(
    const us_t* __restrict__ tbuf, const float* __restrict__ W2,
    const float* __restrict__ b2v, const us_t* __restrict__ xin,
    const float* __restrict__ x, float* __restrict__ out0, float* __restrict__ out1,
    int r_base)
{
  __shared__ __align__(16) us_t W2s[192*64];
  __shared__ __align__(16) us_t ts[192*68];   // [f][row]
  int t = threadIdx.x;
  int n = blockIdx.x >> 2, rt = blockIdx.x & 3;
  const float* wsrc = W2 + (size_t)n*12288;
  #pragma unroll
  for (int i = 0; i < 12; i++){   // W2 fp32 -> bf16 LDS
    int idx = (i*256 + t)*4;
    float4 w = *(const float4*)(wsrc + idx);
    *(uint2*)&W2s[idx] = make_uint2(pack2(w.x,w.y), pack2(w.z,w.w));
  }
  #pragma unroll
  for (int i = 0; i < 6; i++){
    int chunk = i*256 + t;
    int rr = chunk/24, ff0 = (chunk - rr*24)*8;
    uint4 d = *(const uint4*)(tbuf + ((size_t)(rt*64 + rr)*256 + n)*192 + ff0);
    us_t* dst = &ts[ff0*68 + rr];
    dst[0]    = (us_t)d.x; dst[68]   = (us_t)(d.x>>16);
    dst[2*68] = (us_t)d.y; dst[3*68] = (us_t)(d.y>>16);
    dst[4*68] = (us_t)d.z; dst[5*68] = (us_t)(d.z>>16);
    dst[6*68] = (us_t)d.w; dst[7*68] = (us_t)(d.w>>16);
  }
  __syncthreads();
  int cg = t & 15, rg = t >> 4;
  int c0 = cg*4, rr0 = rg*4;
  float acc[4][4] = {};
  #pragma unroll 4
  for (int f = 0; f < 192; f++){
    uint2 au = *(const uint2*)&ts[f*68 + rr0];
    uint2 wu = *(const uint2*)&W2s[f*64 + c0];
    float a0 = lo2f(au.x), a1 = hi2f(au.x), a2 = lo2f(au.y), a3 = hi2f(au.y);
    float w0 = lo2f(wu.x), w1 = hi2f(wu.x), w2 = lo2f(wu.y), w3 = hi2f(wu.y);
    acc[0][0] += a0*w0; acc[0][1] += a0*w1; acc[0][2] += a0*w2; acc[0][3] += a0*w3;
    acc[1][0] += a1*w0; acc[1][1] += a1*w1; acc[1][2] += a1*w2; acc[1][3] += a1*w3;
    acc[2][0] += a2*w0; acc[2][1] += a2*w1; acc[2][2] += a2*w2; acc[2][3] += a2*w3;
    acc[3][0] += a3*w0; acc[3][1] += a3*w1; acc[3][2] += a3*w2; acc[3][3] += a3*w3;
  }
  float4 bb = *(const float4*)(b2v + n*64 + c0);
  #pragma unroll
  for (int i = 0; i < 4; i++){
    int rl = rt*64 + rr0 + i;                  // chunk-local
    int r = r_base + rl;                       // global row
    int branch = r >> 9, bidx = (r >> 8) & 1, g = r & 255;
    uint2 xi = *(const uint2*)(xin + ((size_t)r*256 + n)*64 + c0);
    float v0 = acc[i][0] + bb.x + lo2f(xi.x);
    float v1 = acc[i][1] + bb.y + hi2f(xi.x);
    float v2 = acc[i][2] + bb.z + lo2f(xi.y);
    float v3 = acc[i][3] + bb.w + hi2f(xi.y);
    int h, w;
    if (branch == 0){ h = ((n >> 4) << 4) | (g >> 4); w = ((n & 15) << 4) | (g & 15); }  // recon_grids
    else            { h = ((g >> 4) << 4) | (n >> 4); w = ((g & 15) << 4) | (n & 15); }  // recon_blocks
    size_t base = (size_t)(bidx*256 + h)*256 + w;
    size_t o0idx = base*128 + (branch << 6) + c0;
    float4 xr = *(const float4*)(x + o0idx);
    *(float4*)(out0 + o0idx) = make_float4(v0 + xr.x, v1 + xr.y, v2 + xr.z, v3 + xr.w);
    if (branch){
      *(float4*)(out1 + base*64 + c0) = make_float4(v0, v1, v2, v3);
    }
  }
}

// ---------------------------------------------------------------- launch
extern "C" void kernel_launch(void* const* d_in, const int* in_sizes, int n_in,
                              void* d_out, int out_size, void* d_ws, size_t ws_size,
                              hipStream_t stream)
{
  (void)in_sizes; (void)n_in; (void)out_size; (void)ws_size;
  const float* x    = (const float*)d_in[0];
  const float* g1   = (const float*)d_in[1];
  const float* b1l  = (const float*)d_in[2];
  const float* Wp   = (const float*)d_in[3];
  const float* bp   = (const float*)d_in[4];
  const float* g2   = (const float*)d_in[5];
  const float* b2l  = (const float*)d_in[6];
  const float* W1   = (const float*)d_in[7];
  const float* b1v  = (const float*)d_in[8];
  const float* g3   = (const float*)d_in[9];
  const float* b3l  = (const float*)d_in[10];
  const float* Wsgu = (const float*)d_in[11];
  const float* bsgu = (const float*)d_in[12];
  const float* W2   = (const float*)d_in[13];
  const float* b2v  = (const float*)d_in[14];

  float* out0 = (float*)d_out;
  float* out1 = out0 + (size_t)2*256*256*128;

  us_t* ws   = (us_t*)d_ws;
  us_t* xin  = ws;                       // [1024][256][64]        16,777,216
  us_t* bufA = ws + 16777216;            // u_ln -> sT (chunk)     12,582,912
  us_t* bufV = bufA + 12582912;          // v (chunk)              12,582,912
  us_t* bufB = bufV + 12582912;          // uT -> t (chunk)        12,582,912

  k1_ln_proj <<<dim3(4096), dim3(256), 0, stream>>>(x, g1, b1l, Wp, bp, xin);
  for (int chunk = 0; chunk < 4; ++chunk){
    int r_base = chunk * 256;
    k2_e1      <<<dim3(2048), dim3(256), 0, stream>>>(xin, g2, b2l, W1, b1v, g3, b3l, bufA, bufV, r_base);
    t1_transpose<<<dim3(512),  dim3(256), 0, stream>>>(bufA, bufB);
    k3_sgu     <<<dim3(768),  dim3(256), 0, stream>>>(bufB, Wsgu, bsgu, bufA);
    t2_mul     <<<dim3(512),  dim3(256), 0, stream>>>(bufA, bufV, bufB);
    k4_out     <<<dim3(1024), dim3(256), 0, stream>>>(bufB, W2, b2v, xin, x, out0, out1, r_base);
  }
}

// Round 5
// 1196.506 us; speedup vs baseline: 1.1044x; 1.1044x over previous
//
#include <hip/hip_runtime.h>

// MAB (gMLP mixing block) — round 5: fix K3 MFMA LDS staging (was only
// filling 64 of 128 tile rows -> uninitialized-LDS NaN), and de-risk
// workspace: 8 chunks of 128 rows, total ws 96.5MB (< 104MB proven good).
//
// Dims: B=2, H=W=256, C=128, S=16, G=256, N=256, CI=64, F1=384, HF=192.
// Rows R = 1024; chunk RC = 128.
//
//  WP: Wsgu fp32 [c][k][m] -> WT bf16 [c][m][k]  (once; k-contig for B-frag)
//  K1: LN1 + [131072x128]x[128x128] GEMM + GELU -> xin[r][n][ci]   (full)
//  per chunk (128 rows):
//   K2: LN2 + per-n E1 + GELU + LN3(u) -> u_ln[r][n][f], v[r][n][f]
//   T1: u_ln -> uT[c][r][n]
//   K3: per-c SGU [128x256]x[256x256] via mfma_f32_16x16x32_bf16 -> sT[c][r][m]
//   T2: t[r][m][c] = sT[c][r][m] * v[r][m][c]
//   K4: per-n E2 + b2 + xin residual + recon/concat + outer residual (fp32 out)
//
// ws (bf16 elems): xin 16,777,216 | bufA 6,291,456 | bufV 6,291,456 |
// bufB 6,291,456 | WT 12,582,912  => 96,468,992 bytes.

typedef unsigned int uint_t;
typedef unsigned short us_t;
typedef __attribute__((ext_vector_type(8))) short bf16x8;
typedef __attribute__((ext_vector_type(4))) float f32x4;

#define EPSF 1e-3f

__device__ __forceinline__ float b2f(us_t h){ return __uint_as_float(((uint_t)h) << 16); }
__device__ __forceinline__ float lo2f(uint_t u){ return __uint_as_float(u << 16); }
__device__ __forceinline__ float hi2f(uint_t u){ return __uint_as_float(u & 0xFFFF0000u); }
__device__ __forceinline__ us_t f2b(float f){
  uint_t u = __float_as_uint(f);
  uint_t r = (u + 0x7FFFu + ((u >> 16) & 1u)) >> 16;
  return (us_t)r;
}
__device__ __forceinline__ uint_t pack2(float a, float b){
  return (uint_t)f2b(a) | ((uint_t)f2b(b) << 16);
}
__device__ __forceinline__ float gelu_f(float v){
  return 0.5f*v*(1.f + erff(v*0.7071067811865475f));
}

// ---------------------------------------------------------------- WP
// Wsgu fp32 [c][k][m] -> WT bf16 [c][m][k]; block = (c, 64-k tile)
__global__ __launch_bounds__(256) void wprep(const float* __restrict__ Wsgu, us_t* __restrict__ WT){
  __shared__ us_t ls[64*264];
  int t = threadIdx.x;
  int c = blockIdx.x >> 2, kt = blockIdx.x & 3;
  const float* src = Wsgu + ((size_t)c*256 + kt*64)*256;
  #pragma unroll
  for (int i = 0; i < 16; i++){
    int chunk = i*256 + t;
    int kk = chunk >> 6, mm = (chunk & 63) << 2;
    float4 w = *(const float4*)(src + kk*256 + mm);
    *(uint2*)&ls[kk*264 + mm] = make_uint2(pack2(w.x,w.y), pack2(w.z,w.w));
  }
  __syncthreads();
  #pragma unroll
  for (int i = 0; i < 8; i++){
    int chunk = i*256 + t;
    int m = chunk >> 3, kk0 = (chunk & 7) << 3;
    const us_t* sp = &ls[kk0*264 + m];
    uint4 o;
    o.x = (uint_t)sp[0]     | ((uint_t)sp[264]   << 16);
    o.y = (uint_t)sp[2*264] | ((uint_t)sp[3*264] << 16);
    o.z = (uint_t)sp[4*264] | ((uint_t)sp[5*264] << 16);
    o.w = (uint_t)sp[6*264] | ((uint_t)sp[7*264] << 16);
    *(uint4*)(WT + ((size_t)c*256 + m)*256 + kt*64 + kk0) = o;
  }
}

// ---------------------------------------------------------------- K1
__global__ __launch_bounds__(256) void k1_ln_proj(
    const float* __restrict__ x, const float* __restrict__ g1, const float* __restrict__ b1l,
    const float* __restrict__ Wp, const float* __restrict__ bp, us_t* __restrict__ xin)
{
  __shared__ __align__(16) float xs2[128*40];   // [c][pix], stride 40
  __shared__ __align__(16) us_t Ws[128*128];
  int t = threadIdx.x;
  int p0 = blockIdx.x * 32;

  { // stage x transposed
    int pi = t >> 3, c0 = (t & 7) << 4;
    const float* src = x + (size_t)(p0 + pi)*128 + c0;
    float4 d0 = *(const float4*)src;
    float4 d1 = *(const float4*)(src + 4);
    float4 d2 = *(const float4*)(src + 8);
    float4 d3 = *(const float4*)(src + 12);
    float* dst = &xs2[c0*40 + pi];
    dst[0]   = d0.x; dst[40]  = d0.y; dst[80]  = d0.z; dst[120] = d0.w;
    dst[160] = d1.x; dst[200] = d1.y; dst[240] = d1.z; dst[280] = d1.w;
    dst[320] = d2.x; dst[360] = d2.y; dst[400] = d2.z; dst[440] = d2.w;
    dst[480] = d3.x; dst[520] = d3.y; dst[560] = d3.z; dst[600] = d3.w;
  }
  #pragma unroll
  for (int i = 0; i < 16; i++){   // Wp fp32 -> bf16 LDS
    int idx = (i*256 + t)*4;
    float4 w = *(const float4*)(Wp + idx);
    *(uint2*)&Ws[idx] = make_uint2(pack2(w.x,w.y), pack2(w.z,w.w));
  }
  __syncthreads();
  { // LN1
    int wv = t >> 6, ln = t & 63;
    float ga = g1[ln], gb = g1[ln+64];
    float ba = b1l[ln], bb = b1l[ln+64];
    for (int k = 0; k < 8; k++){
      int pi = wv*8 + k;
      float a = xs2[ln*40 + pi];
      float c = xs2[(ln+64)*40 + pi];
      float s = a + c, q = a*a + c*c;
      #pragma unroll
      for (int off = 32; off; off >>= 1){ s += __shfl_xor(s, off, 64); q += __shfl_xor(q, off, 64); }
      float m = s*(1.f/128.f);
      float rstd = rsqrtf(q*(1.f/128.f) - m*m + EPSF);
      xs2[ln*40 + pi]      = (a - m)*rstd*ga + ba;
      xs2[(ln+64)*40 + pi] = (c - m)*rstd*gb + bb;
    }
  }
  __syncthreads();
  int cg = t & 31, pg = t >> 5;
  int co0 = cg*4, p00 = pg*4;
  float acc[4][4] = {};
  #pragma unroll 4
  for (int ci = 0; ci < 128; ci++){
    float4 xv = *(const float4*)&xs2[ci*40 + p00];
    uint2 wv2 = *(const uint2*)&Ws[ci*128 + co0];
    float w0 = lo2f(wv2.x), w1 = hi2f(wv2.x), w2 = lo2f(wv2.y), w3 = hi2f(wv2.y);
    acc[0][0] += xv.x*w0; acc[0][1] += xv.x*w1; acc[0][2] += xv.x*w2; acc[0][3] += xv.x*w3;
    acc[1][0] += xv.y*w0; acc[1][1] += xv.y*w1; acc[1][2] += xv.y*w2; acc[1][3] += xv.y*w3;
    acc[2][0] += xv.z*w0; acc[2][1] += xv.z*w1; acc[2][2] += xv.z*w2; acc[2][3] += xv.z*w3;
    acc[3][0] += xv.w*w0; acc[3][1] += xv.w*w1; acc[3][2] += xv.w*w2; acc[3][3] += xv.w*w3;
  }
  float bb0 = bp[co0],   bb1 = bp[co0+1];
  float bb2 = bp[co0+2], bb3 = bp[co0+3];
  int branch = co0 >> 6;
  int c = co0 & 63;
  #pragma unroll
  for (int i = 0; i < 4; i++){
    int p = p0 + p00 + i;
    int b = p >> 16, rem = p & 65535, h = rem >> 8, w = rem & 255;
    int g = ((h >> 4) << 4) | (w >> 4);
    int nn = ((h & 15) << 4) | (w & 15);
    float y0 = gelu_f(acc[i][0] + bb0);
    float y1 = gelu_f(acc[i][1] + bb1);
    float y2 = gelu_f(acc[i][2] + bb2);
    float y3 = gelu_f(acc[i][3] + bb3);
    size_t row = (size_t)branch*512 + (size_t)b*256 + g;
    *(uint2*)(xin + (row*256 + nn)*64 + c) = make_uint2(pack2(y0,y1), pack2(y2,y3));
  }
}

// ---------------------------------------------------------------- K2 (chunk RC=128)
// grid = 256 n x 4 rt
__global__ __launch_bounds__(256) void k2_e1(
    const us_t* __restrict__ xin,
    const float* __restrict__ g2, const float* __restrict__ b2l,
    const float* __restrict__ W1, const float* __restrict__ b1v,
    const float* __restrict__ g3, const float* __restrict__ b3l,
    us_t* __restrict__ u_ln, us_t* __restrict__ vout, int r_base)
{
  __shared__ __align__(16) us_t Wl[64*384];
  __shared__ __align__(16) float xs2[64*36];
  __shared__ float b1s[384];
  int t = threadIdx.x;
  int n = blockIdx.x >> 2, rt = blockIdx.x & 3;

  const float* wsrc = W1 + (size_t)n*24576;
  #pragma unroll
  for (int i = 0; i < 24; i++){   // W1 fp32 -> bf16 LDS
    int idx = (i*256 + t)*4;
    float4 w = *(const float4*)(wsrc + idx);
    *(uint2*)&Wl[idx] = make_uint2(pack2(w.x,w.y), pack2(w.z,w.w));
  }
  if (t < 96){
    float4 d = *(const float4*)(b1v + n*384 + t*4);
    b1s[t*4+0] = d.x; b1s[t*4+1] = d.y; b1s[t*4+2] = d.z; b1s[t*4+3] = d.w;
  }
  {
    int rr = t >> 3, cc0 = (t & 7) << 3;
    uint4 d = *(const uint4*)(xin + ((size_t)(r_base + rt*32 + rr)*256 + n)*64 + cc0);
    float* dst = &xs2[cc0*36 + rr];
    dst[0]    = lo2f(d.x); dst[36]   = hi2f(d.x);
    dst[2*36] = lo2f(d.y); dst[3*36] = hi2f(d.y);
    dst[4*36] = lo2f(d.z); dst[5*36] = hi2f(d.z);
    dst[6*36] = lo2f(d.w); dst[7*36] = hi2f(d.w);
  }
  __syncthreads();
  {
    int wv = t >> 6, ln = t & 63;
    float gch = g2[ln], bch = b2l[ln];
    for (int k = 0; k < 8; k++){
      int row = wv*8 + k;
      float a = xs2[ln*36 + row];
      float s = a, q = a*a;
      #pragma unroll
      for (int off = 32; off; off >>= 1){ s += __shfl_xor(s, off, 64); q += __shfl_xor(q, off, 64); }
      float m = s*(1.f/64.f);
      float rstd = rsqrtf(q*(1.f/64.f) - m*m + EPSF);
      xs2[ln*36 + row] = (a - m)*rstd*gch + bch;
    }
  }
  __syncthreads();
  int fg = t & 31, rg = t >> 5;
  int f0 = fg*12, r00 = rg*4;
  float acc[4][12] = {};
  #pragma unroll 4
  for (int ci = 0; ci < 64; ci++){
    float4 xv = *(const float4*)&xs2[ci*36 + r00];
    const uint2* wp2 = (const uint2*)&Wl[ci*384 + f0];
    uint2 wa = wp2[0], wb = wp2[1], wc = wp2[2];
    float wf[12];
    wf[0]=lo2f(wa.x); wf[1]=hi2f(wa.x); wf[2]=lo2f(wa.y); wf[3]=hi2f(wa.y);
    wf[4]=lo2f(wb.x); wf[5]=hi2f(wb.x); wf[6]=lo2f(wb.y); wf[7]=hi2f(wb.y);
    wf[8]=lo2f(wc.x); wf[9]=hi2f(wc.x); wf[10]=lo2f(wc.y); wf[11]=hi2f(wc.y);
    float xa[4] = {xv.x, xv.y, xv.z, xv.w};
    #pragma unroll
    for (int i = 0; i < 4; i++)
      #pragma unroll
      for (int j = 0; j < 12; j++)
        acc[i][j] += xa[i]*wf[j];
  }
  bool isu = (fg < 16);
  float s4[4], q4[4];
  #pragma unroll
  for (int i = 0; i < 4; i++){
    float s = 0.f, q = 0.f;
    #pragma unroll
    for (int j = 0; j < 12; j++){
      float yv = gelu_f(acc[i][j] + b1s[f0 + j]);
      acc[i][j] = yv;
      s += yv; q += yv*yv;
    }
    s4[i] = isu ? s : 0.f;
    q4[i] = isu ? q : 0.f;
  }
  #pragma unroll
  for (int i = 0; i < 4; i++){
    float s = s4[i], q = q4[i];
    #pragma unroll
    for (int off = 16; off; off >>= 1){ s += __shfl_xor(s, off, 64); q += __shfl_xor(q, off, 64); }
    float m = s*(1.f/192.f);
    s4[i] = m;
    q4[i] = rsqrtf(q*(1.f/192.f) - m*m + EPSF);
  }
  if (isu){
    float gv[12], bv[12];
    #pragma unroll
    for (int j = 0; j < 12; j++){ gv[j] = g3[f0+j]; bv[j] = b3l[f0+j]; }
    #pragma unroll
    for (int i = 0; i < 4; i++){
      int r = rt*32 + r00 + i;                 // chunk-local 0..127
      float m = s4[i], rstd = q4[i];
      uint2* dst = (uint2*)(u_ln + ((size_t)r*256 + n)*192 + f0);
      uint2 o0, o1, o2;
      o0.x = pack2((acc[i][0]-m)*rstd*gv[0]+bv[0],  (acc[i][1]-m)*rstd*gv[1]+bv[1]);
      o0.y = pack2((acc[i][2]-m)*rstd*gv[2]+bv[2],  (acc[i][3]-m)*rstd*gv[3]+bv[3]);
      o1.x = pack2((acc[i][4]-m)*rstd*gv[4]+bv[4],  (acc[i][5]-m)*rstd*gv[5]+bv[5]);
      o1.y = pack2((acc[i][6]-m)*rstd*gv[6]+bv[6],  (acc[i][7]-m)*rstd*gv[7]+bv[7]);
      o2.x = pack2((acc[i][8]-m)*rstd*gv[8]+bv[8],  (acc[i][9]-m)*rstd*gv[9]+bv[9]);
      o2.y = pack2((acc[i][10]-m)*rstd*gv[10]+bv[10],(acc[i][11]-m)*rstd*gv[11]+bv[11]);
      dst[0] = o0; dst[1] = o1; dst[2] = o2;
    }
  } else {
    int fv0 = f0 - 192;
    #pragma unroll
    for (int i = 0; i < 4; i++){
      int r = rt*32 + r00 + i;                 // chunk-local 0..127
      uint2* dst = (uint2*)(vout + ((size_t)r*256 + n)*192 + fv0);
      uint2 o0, o1, o2;
      o0.x = pack2(acc[i][0], acc[i][1]);  o0.y = pack2(acc[i][2], acc[i][3]);
      o1.x = pack2(acc[i][4], acc[i][5]);  o1.y = pack2(acc[i][6], acc[i][7]);
      o2.x = pack2(acc[i][8], acc[i][9]);  o2.y = pack2(acc[i][10], acc[i][11]);
      dst[0] = o0; dst[1] = o1; dst[2] = o2;
    }
  }
}

// ---------------------------------------------------------------- T1 (RC=128)
// u_ln[r][n][c] -> uT[c][r][n], r in [0,128); grid = 128 r x 2 n-halves
__global__ __launch_bounds__(256) void t1_transpose(const us_t* __restrict__ u_ln, us_t* __restrict__ uT){
  __shared__ us_t ls[128*194];
  int t = threadIdx.x;
  int r = blockIdx.x >> 1, n0 = (blockIdx.x & 1) << 7;
  #pragma unroll
  for (int i = 0; i < 12; i++){
    int chunk = i*256 + t;
    int nn = chunk/24, c0 = (chunk - nn*24)*8;
    uint4 d = *(const uint4*)(u_ln + ((size_t)r*256 + n0 + nn)*192 + c0);
    us_t* dst = &ls[nn*194 + c0];
    dst[0] = (us_t)d.x; dst[1] = (us_t)(d.x>>16);
    dst[2] = (us_t)d.y; dst[3] = (us_t)(d.y>>16);
    dst[4] = (us_t)d.z; dst[5] = (us_t)(d.z>>16);
    dst[6] = (us_t)d.w; dst[7] = (us_t)(d.w>>16);
  }
  __syncthreads();
  #pragma unroll
  for (int i = 0; i < 12; i++){
    int chunk = i*256 + t;
    int c = chunk >> 4, nn0 = (chunk & 15) << 3;
    const us_t* sp = &ls[nn0*194 + c];
    uint4 o;
    o.x = (uint_t)sp[0]     | ((uint_t)sp[194]   << 16);
    o.y = (uint_t)sp[2*194] | ((uint_t)sp[3*194] << 16);
    o.z = (uint_t)sp[4*194] | ((uint_t)sp[5*194] << 16);
    o.w = (uint_t)sp[6*194] | ((uint_t)sp[7*194] << 16);
    *(uint4*)(uT + ((size_t)c*128 + r)*256 + n0 + nn0) = o;
  }
}

// ---------------------------------------------------------------- K3 (RC=128, MFMA)
// per-c SGU: S[r][m] = sum_k U[r][k] W[k][m]; 128x256x256 per c, bf16 MFMA.
// grid = 192 c x 2 mt; block tile 128r x 128m; wave = 64x64; BK=64.
// A = uT[c][r][k] (k-contig); B^T = WT[c][m][k] (k-contig).
__global__ __launch_bounds__(256) void k3_sgu_mfma(
    const us_t* __restrict__ uT, const us_t* __restrict__ WT,
    const float* __restrict__ bsgu, us_t* __restrict__ sT)
{
  __shared__ __align__(16) us_t As[128*72];
  __shared__ __align__(16) us_t Bs[128*72];
  int t = threadIdx.x;
  int c = blockIdx.x >> 1, mt = blockIdx.x & 1;
  int lane = t & 63, wv = t >> 6;
  int wr0 = (wv >> 1) * 64, wm0 = (wv & 1) * 64;
  int fr = lane & 15, fq = lane >> 4;          // frag row / k-quad
  f32x4 acc[4][4] = {};                         // [mi][ni]

  const us_t* aSrc = uT + (size_t)c*128*256;
  const us_t* bSrc = WT + ((size_t)(c*256 + mt*128))*256;

  for (int ks = 0; ks < 256; ks += 64){
    #pragma unroll
    for (int i = 0; i < 4; i++){               // 128 rows x 64 k per array
      int chunk = i*256 + t;
      int rr = chunk >> 3, kk = (chunk & 7) << 3;
      *(uint4*)&As[rr*72 + kk] = *(const uint4*)(aSrc + rr*256 + ks + kk);
      *(uint4*)&Bs[rr*72 + kk] = *(const uint4*)(bSrc + rr*256 + ks + kk);
    }
    __syncthreads();
    #pragma unroll
    for (int s = 0; s < 2; s++){
      int kb = s*32 + fq*8;
      bf16x8 a[4], b[4];
      #pragma unroll
      for (int mi = 0; mi < 4; mi++)
        a[mi] = *(const bf16x8*)&As[(wr0 + mi*16 + fr)*72 + kb];
      #pragma unroll
      for (int ni = 0; ni < 4; ni++)
        b[ni] = *(const bf16x8*)&Bs[(wm0 + ni*16 + fr)*72 + kb];
      #pragma unroll
      for (int mi = 0; mi < 4; mi++)
        #pragma unroll
        for (int ni = 0; ni < 4; ni++)
          acc[mi][ni] = __builtin_amdgcn_mfma_f32_16x16x32_bf16(a[mi], b[ni], acc[mi][ni], 0, 0, 0);
    }
    __syncthreads();
  }
  // epilogue: D[row=wr0+mi*16+fq*4+i][col=wm0+ni*16+fr] + bsgu[c][m]
  float bsv[4];
  #pragma unroll
  for (int ni = 0; ni < 4; ni++)
    bsv[ni] = bsgu[c*256 + mt*128 + wm0 + ni*16 + fr];
  #pragma unroll
  for (int mi = 0; mi < 4; mi++){
    #pragma unroll
    for (int i = 0; i < 4; i++){
      int r = wr0 + mi*16 + fq*4 + i;          // 0..127
      us_t* dst = sT + ((size_t)c*128 + r)*256 + mt*128 + wm0 + fr;
      #pragma unroll
      for (int ni = 0; ni < 4; ni++)
        dst[ni*16] = f2b(acc[mi][ni][i] + bsv[ni]);
    }
  }
}

// ---------------------------------------------------------------- T2 (RC=128)
// t[r][m][c] = sT[c][r][m] * v[r][m][c], r in [0,128)
__global__ __launch_bounds__(256) void t2_mul(
    const us_t* __restrict__ sT, const us_t* __restrict__ v, us_t* __restrict__ tout)
{
  __shared__ us_t ls[192*130];
  int t = threadIdx.x;
  int r = blockIdx.x >> 1, m0 = (blockIdx.x & 1) << 7;
  #pragma unroll
  for (int i = 0; i < 12; i++){
    int chunk = i*256 + t;
    int c = chunk >> 4, mm0 = (chunk & 15) << 3;
    uint4 d = *(const uint4*)(sT + ((size_t)c*128 + r)*256 + m0 + mm0);
    us_t* dst = &ls[c*130 + mm0];
    dst[0] = (us_t)d.x; dst[1] = (us_t)(d.x>>16);
    dst[2] = (us_t)d.y; dst[3] = (us_t)(d.y>>16);
    dst[4] = (us_t)d.z; dst[5] = (us_t)(d.z>>16);
    dst[6] = (us_t)d.w; dst[7] = (us_t)(d.w>>16);
  }
  __syncthreads();
  #pragma unroll
  for (int i = 0; i < 12; i++){
    int chunk = i*256 + t;
    int mm = chunk/24, c0 = (chunk - mm*24)*8;
    size_t gidx = ((size_t)r*256 + m0 + mm)*192 + c0;
    uint4 vv = *(const uint4*)(v + gidx);
    const us_t* sp = &ls[c0*130 + mm];
    uint4 o;
    o.x = pack2(b2f(sp[0])*lo2f(vv.x),     b2f(sp[130])*hi2f(vv.x));
    o.y = pack2(b2f(sp[2*130])*lo2f(vv.y), b2f(sp[3*130])*hi2f(vv.y));
    o.z = pack2(b2f(sp[4*130])*lo2f(vv.z), b2f(sp[5*130])*hi2f(vv.z));
    o.w = pack2(b2f(sp[6*130])*lo2f(vv.w), b2f(sp[7*130])*hi2f(vv.w));
    *(uint4*)(tout + gidx) = o;
  }
}

// ---------------------------------------------------------------- K4 (RC=128)
// grid = 256 n x 2 rt
__global__ __launch_bounds__(256) void k4_out(
    const us_t* __restrict__ tbuf, const float* __restrict__ W2,
    const float* __restrict__ b2v, const us_t* __restrict__ xin,
    const float* __restrict__ x, float* __restrict__ out0, float* __restrict__ out1,
    int r_base)
{
  __shared__ __align__(16) us_t W2s[192*64];
  __shared__ __align__(16) us_t ts[192*68];   // [f][row]
  int t = threadIdx.x;
  int n = blockIdx.x >> 1, rt = blockIdx.x & 1;
  const float* wsrc = W2 + (size_t)n*12288;
  #pragma unroll
  for (int i = 0; i < 12; i++){   // W2 fp32 -> bf16 LDS
    int idx = (i*256 + t)*4;
    float4 w = *(const float4*)(wsrc + idx);
    *(uint2*)&W2s[idx] = make_uint2(pack2(w.x,w.y), pack2(w.z,w.w));
  }
  #pragma unroll
  for (int i = 0; i < 6; i++){
    int chunk = i*256 + t;
    int rr = chunk/24, ff0 = (chunk - rr*24)*8;
    uint4 d = *(const uint4*)(tbuf + ((size_t)(rt*64 + rr)*256 + n)*192 + ff0);
    us_t* dst = &ts[ff0*68 + rr];
    dst[0]    = (us_t)d.x; dst[68]   = (us_t)(d.x>>16);
    dst[2*68] = (us_t)d.y; dst[3*68] = (us_t)(d.y>>16);
    dst[4*68] = (us_t)d.z; dst[5*68] = (us_t)(d.z>>16);
    dst[6*68] = (us_t)d.w; dst[7*68] = (us_t)(d.w>>16);
  }
  __syncthreads();
  int cg = t & 15, rg = t >> 4;
  int c0 = cg*4, rr0 = rg*4;
  float acc[4][4] = {};
  #pragma unroll 4
  for (int f = 0; f < 192; f++){
    uint2 au = *(const uint2*)&ts[f*68 + rr0];
    uint2 wu = *(const uint2*)&W2s[f*64 + c0];
    float a0 = lo2f(au.x), a1 = hi2f(au.x), a2 = lo2f(au.y), a3 = hi2f(au.y);
    float w0 = lo2f(wu.x), w1 = hi2f(wu.x), w2 = lo2f(wu.y), w3 = hi2f(wu.y);
    acc[0][0] += a0*w0; acc[0][1] += a0*w1; acc[0][2] += a0*w2; acc[0][3] += a0*w3;
    acc[1][0] += a1*w0; acc[1][1] += a1*w1; acc[1][2] += a1*w2; acc[1][3] += a1*w3;
    acc[2][0] += a2*w0; acc[2][1] += a2*w1; acc[2][2] += a2*w2; acc[2][3] += a2*w3;
    acc[3][0] += a3*w0; acc[3][1] += a3*w1; acc[3][2] += a3*w2; acc[3][3] += a3*w3;
  }
  float4 bb = *(const float4*)(b2v + n*64 + c0);
  #pragma unroll
  for (int i = 0; i < 4; i++){
    int rl = rt*64 + rr0 + i;                  // chunk-local 0..127
    int r = r_base + rl;                       // global row
    int branch = r >> 9, bidx = (r >> 8) & 1, g = r & 255;
    uint2 xi = *(const uint2*)(xin + ((size_t)r*256 + n)*64 + c0);
    float v0 = acc[i][0] + bb.x + lo2f(xi.x);
    float v1 = acc[i][1] + bb.y + hi2f(xi.x);
    float v2 = acc[i][2] + bb.z + lo2f(xi.y);
    float v3 = acc[i][3] + bb.w + hi2f(xi.y);
    int h, w;
    if (branch == 0){ h = ((n >> 4) << 4) | (g >> 4); w = ((n & 15) << 4) | (g & 15); }
    else            { h = ((g >> 4) << 4) | (n >> 4); w = ((g & 15) << 4) | (n & 15); }
    size_t base = (size_t)(bidx*256 + h)*256 + w;
    size_t o0idx = base*128 + (branch << 6) + c0;
    float4 xr = *(const float4*)(x + o0idx);
    *(float4*)(out0 + o0idx) = make_float4(v0 + xr.x, v1 + xr.y, v2 + xr.z, v3 + xr.w);
    if (branch){
      *(float4*)(out1 + base*64 + c0) = make_float4(v0, v1, v2, v3);
    }
  }
}

// ---------------------------------------------------------------- launch
extern "C" void kernel_launch(void* const* d_in, const int* in_sizes, int n_in,
                              void* d_out, int out_size, void* d_ws, size_t ws_size,
                              hipStream_t stream)
{
  (void)in_sizes; (void)n_in; (void)out_size; (void)ws_size;
  const float* x    = (const float*)d_in[0];
  const float* g1   = (const float*)d_in[1];
  const float* b1l  = (const float*)d_in[2];
  const float* Wp   = (const float*)d_in[3];
  const float* bp   = (const float*)d_in[4];
  const float* g2   = (const float*)d_in[5];
  const float* b2l  = (const float*)d_in[6];
  const float* W1   = (const float*)d_in[7];
  const float* b1v  = (const float*)d_in[8];
  const float* g3   = (const float*)d_in[9];
  const float* b3l  = (const float*)d_in[10];
  const float* Wsgu = (const float*)d_in[11];
  const float* bsgu = (const float*)d_in[12];
  const float* W2   = (const float*)d_in[13];
  const float* b2v  = (const float*)d_in[14];

  float* out0 = (float*)d_out;
  float* out1 = out0 + (size_t)2*256*256*128;

  us_t* ws   = (us_t*)d_ws;
  us_t* xin  = ws;                       // [1024][256][64]        16,777,216
  us_t* bufA = ws + 16777216;            // u_ln -> sT (chunk)      6,291,456
  us_t* bufV = bufA + 6291456;           // v (chunk)               6,291,456
  us_t* bufB = bufV + 6291456;           // uT -> t (chunk)         6,291,456
  us_t* WT   = bufB + 6291456;           // Wsgu^T bf16 [c][m][k]  12,582,912

  wprep      <<<dim3(768),  dim3(256), 0, stream>>>(Wsgu, WT);
  k1_ln_proj <<<dim3(4096), dim3(256), 0, stream>>>(x, g1, b1l, Wp, bp, xin);
  for (int chunk = 0; chunk < 8; ++chunk){
    int r_base = chunk * 128;
    k2_e1       <<<dim3(1024), dim3(256), 0, stream>>>(xin, g2, b2l, W1, b1v, g3, b3l, bufA, bufV, r_base);
    t1_transpose<<<dim3(256),  dim3(256), 0, stream>>>(bufA, bufB);
    k3_sgu_mfma <<<dim3(384),  dim3(256), 0, stream>>>(bufB, WT, bsgu, bufA);
    t2_mul      <<<dim3(256),  dim3(256), 0, stream>>>(bufA, bufV, bufB);
    k4_out      <<<dim3(512),  dim3(256), 0, stream>>>(bufB, W2, b2v, xin, x, out0, out1, r_base);
  }
}